// Round 3
// baseline (11181.419 us; speedup 1.0000x reference)
//
#include <hip/hip_runtime.h>

#define NR 512
#define NZ 512

// ---------------- tiled LDS kernel ----------------
#define T_TILES 8
#define ROWS_PER_TILE 64            // ir0 range per tile
#define TILE_ROWS 65                // staged rows (incl. +1 boundary row)
#define TILE_ELEMS (TILE_ROWS * NZ) // 33280 floats
#define TILE_BYTES (TILE_ELEMS * 4) // 133120 B of dynamic LDS
#define BLOCK 1024
#define KQ 16                       // queries per thread
#define CHUNK (BLOCK * KQ)          // 16384 queries per workgroup

extern __shared__ float lds_tile[];

__global__ void __launch_bounds__(BLOCK) interp_tiles(
    const float* __restrict__ r, const float* __restrict__ z,
    const float* __restrict__ tt, float* __restrict__ out, int n) {
    const int tid = threadIdx.x;
    const int chunk_base = blockIdx.x * CHUNK;
    const bool full = (chunk_base + CHUNK) <= n;

    // ---- phase 0: load K queries, precompute packed addr + weights ----
    // pk[j] = (tileid << 16) | (lrow*NZ + iz0)   (<= 63*512+511 = 32767, 15 bits)
    // invalid queries get pk = 0xFFFFFFFF (tile field 0xFFFF never matches)
    unsigned pk[KQ];
    float dxv[KQ], dzv[KQ], res[KQ];

#pragma unroll
    for (int jj = 0; jj < KQ / 4; ++jj) {
        const int gi = chunk_base + jj * (BLOCK * 4) + tid * 4;
        float4 rv, zv;
        if (full) {
            rv = reinterpret_cast<const float4*>(r)[gi >> 2];
            zv = reinterpret_cast<const float4*>(z)[gi >> 2];
        } else {
            rv.x = (gi + 0 < n) ? r[gi + 0] : 0.f;
            rv.y = (gi + 1 < n) ? r[gi + 1] : 0.f;
            rv.z = (gi + 2 < n) ? r[gi + 2] : 0.f;
            rv.w = (gi + 3 < n) ? r[gi + 3] : 0.f;
            zv.x = (gi + 0 < n) ? z[gi + 0] : 0.f;
            zv.y = (gi + 1 < n) ? z[gi + 1] : 0.f;
            zv.z = (gi + 2 < n) ? z[gi + 2] : 0.f;
            zv.w = (gi + 3 < n) ? z[gi + 3] : 0.f;
        }
        const float rr[4] = {rv.x, rv.y, rv.z, rv.w};
        const float zz[4] = {zv.x, zv.y, zv.z, zv.w};
#pragma unroll
        for (int c = 0; c < 4; ++c) {
            const int j = jj * 4 + c;
            int ir0 = (int)floorf(rr[c]);
            int iz0 = (int)floorf(zz[c]);
            ir0 = min(max(ir0, 0), NR - 2);
            iz0 = min(max(iz0, 0), NZ - 2);
            dxv[j] = rr[c] - (float)ir0;
            dzv[j] = zz[c] - (float)iz0;
            const int t = ir0 >> 6;                 // tile id 0..7
            const int lrow = ir0 - (t << 6);        // 0..63
            unsigned p = ((unsigned)t << 16) | (unsigned)(lrow * NZ + iz0);
            if (!full && gi + c >= n) p = 0xFFFFFFFFu;
            pk[j] = p;
            res[j] = 0.f;
        }
    }

    // ---- tile loop ----
    for (int t = 0; t < T_TILES; ++t) {
        const int tile_base = t * ROWS_PER_TILE * NZ;                  // element offset
        const int tile_vec4 = min(TILE_ELEMS, NR * NZ - tile_base) / 4; // 8320 (t<7), 8192 (t=7)
        __syncthreads();  // previous tile fully consumed
        const float4* src4 = reinterpret_cast<const float4*>(tt + tile_base);
        float4* dst4 = reinterpret_cast<float4*>(lds_tile);
        for (int i = tid; i < tile_vec4; i += BLOCK) dst4[i] = src4[i];
        __syncthreads();

#pragma unroll
        for (int j = 0; j < KQ; ++j) {
            if ((pk[j] >> 16) == (unsigned)t) {
                const int a = (int)(pk[j] & 0xFFFFu);
                const float q11 = lds_tile[a];
                const float q12 = lds_tile[a + 1];
                const float q21 = lds_tile[a + NZ];
                const float q22 = lds_tile[a + NZ + 1];
                const float wx = 1.0f - dxv[j];
                const float wz = 1.0f - dzv[j];
                res[j] = (q11 * wz + q12 * dzv[j]) * wx +
                         (q21 * wz + q22 * dzv[j]) * dxv[j];
            }
        }
    }

    // ---- coalesced output ----
    if (full) {
#pragma unroll
        for (int jj = 0; jj < KQ / 4; ++jj) {
            const int gi = chunk_base + jj * (BLOCK * 4) + tid * 4;
            float4 o = make_float4(res[jj * 4 + 0], res[jj * 4 + 1],
                                   res[jj * 4 + 2], res[jj * 4 + 3]);
            reinterpret_cast<float4*>(out)[gi >> 2] = o;
        }
    } else {
#pragma unroll
        for (int jj = 0; jj < KQ / 4; ++jj) {
            const int gi = chunk_base + jj * (BLOCK * 4) + tid * 4;
#pragma unroll
            for (int c = 0; c < 4; ++c)
                if (gi + c < n) out[gi + c] = res[jj * 4 + c];
        }
    }
}

// ---------------- fallback: R2 packed-gather path ----------------
#define P_ROWS (NR - 1)
#define P_ELEMS (P_ROWS * NZ)

__global__ void __launch_bounds__(256) build_pack_kernel(
    const float* __restrict__ tt, float2* __restrict__ P) {
    int i = blockIdx.x * blockDim.x + threadIdx.x;
    if (i < P_ELEMS) {
        float2 v;
        v.x = tt[i];
        v.y = tt[i + NZ];
        P[i] = v;
    }
}

__device__ __forceinline__ float interp_packed(float r, float z,
                                               const float2* __restrict__ P) {
    int ir0 = (int)floorf(r);
    int iz0 = (int)floorf(z);
    ir0 = min(max(ir0, 0), NR - 2);
    iz0 = min(max(iz0, 0), NZ - 2);
    float dx = r - (float)ir0;
    float wx = 1.0f - dx;
    float dz = z - (float)iz0;
    float wz = 1.0f - dz;
    int base = ir0 * NZ + iz0;
    float4 q = *reinterpret_cast<const float4*>(P + base);
    return (q.x * wz + q.z * dz) * wx + (q.y * wz + q.w * dz) * dx;
}

__global__ void __launch_bounds__(256) interp_packed_kernel(
    const float* __restrict__ r, const float* __restrict__ z,
    const float2* __restrict__ P, float* __restrict__ out, int n4) {
    int i = blockIdx.x * blockDim.x + threadIdx.x;
    if (i < n4) {
        float4 rv = reinterpret_cast<const float4*>(r)[i];
        float4 zv = reinterpret_cast<const float4*>(z)[i];
        float4 o;
        o.x = interp_packed(rv.x, zv.x, P);
        o.y = interp_packed(rv.y, zv.y, P);
        o.z = interp_packed(rv.z, zv.z, P);
        o.w = interp_packed(rv.w, zv.w, P);
        reinterpret_cast<float4*>(out)[i] = o;
    }
}

__global__ void tail_packed_kernel(const float* __restrict__ r, const float* __restrict__ z,
                                   const float2* __restrict__ P, float* __restrict__ out,
                                   int start, int n) {
    int j = start + blockIdx.x * blockDim.x + threadIdx.x;
    if (j < n) out[j] = interp_packed(r[j], z[j], P);
}

extern "C" void kernel_launch(void* const* d_in, const int* in_sizes, int n_in,
                              void* d_out, int out_size, void* d_ws, size_t ws_size,
                              hipStream_t stream) {
    const float* r  = (const float*)d_in[0];
    const float* z  = (const float*)d_in[1];
    const float* tt = (const float*)d_in[2];
    float* out = (float*)d_out;
    const int n = in_sizes[0];

    // Raise dynamic-LDS limit to 133120 B (idempotent; host-side, not stream-ordered).
    hipError_t attr_ok = hipFuncSetAttribute(
        (const void*)interp_tiles,
        hipFuncAttributeMaxDynamicSharedMemorySize, TILE_BYTES);

    if (attr_ok == hipSuccess) {
        const int blocks = (n + CHUNK - 1) / CHUNK;
        interp_tiles<<<blocks, BLOCK, TILE_BYTES, stream>>>(r, z, tt, out, n);
    } else {
        // fallback: packed 16B-gather path (R2)
        float2* P = (float2*)d_ws;
        const int block = 256;
        const int n4 = n / 4;
        build_pack_kernel<<<(P_ELEMS + block - 1) / block, block, 0, stream>>>(tt, P);
        interp_packed_kernel<<<(n4 + block - 1) / block, block, 0, stream>>>(r, z, P, out, n4);
        const int tail = n - n4 * 4;
        if (tail > 0)
            tail_packed_kernel<<<1, 64, 0, stream>>>(r, z, P, out, n4 * 4, n);
    }
}

// Round 5
// 264.992 us; speedup vs baseline: 42.1953x; 42.1953x over previous
//
#include <hip/hip_runtime.h>

#define NR 512
#define NZ 512
#define P_ELEMS ((NR - 1) * NZ)   // 511*512 records
#define BLOCK 256
#define VPT 2                     // float4 groups per thread -> 8 queries/thread

typedef float vf4 __attribute__((ext_vector_type(4)));
typedef unsigned uv2 __attribute__((ext_vector_type(2)));

// ---- bf16 packing helpers ----
__device__ __forceinline__ unsigned bf16rne(float f) {
    unsigned u = __float_as_uint(f);
    return (u + 0x7FFFu + ((u >> 16) & 1u)) >> 16;   // round-to-nearest-even
}
__device__ __forceinline__ unsigned pack2(float lo, float hi) {
    return bf16rne(lo) | (bf16rne(hi) << 16);
}

// Pb[ir*NZ+iz] = { pack(Q11,Q21), pack(Q12,Q22) }
//   Q11=tt[ir,iz] Q21=tt[ir+1,iz] Q12=tt[ir,iz+1] Q22=tt[ir+1,iz+1]
__global__ void __launch_bounds__(256) build_bf16(
    const float* __restrict__ tt, uv2* __restrict__ Pb) {
    int i = blockIdx.x * 256 + threadIdx.x;
    if (i >= P_ELEMS) return;
    int ir = i >> 9;              // NZ = 512
    int iz = i & 511;
    int izc = min(iz, NZ - 2);    // slot iz=511 never queried; avoid OOB
    float q11 = tt[(ir << 9) + izc];
    float q12 = tt[(ir << 9) + izc + 1];
    float q21 = tt[((ir + 1) << 9) + izc];
    float q22 = tt[((ir + 1) << 9) + izc + 1];
    uv2 v;
    v.x = pack2(q11, q21);
    v.y = pack2(q12, q22);
    Pb[i] = v;
}

__device__ __forceinline__ float interp_one(float rr, float zz,
                                            const uv2* __restrict__ Pb) {
    int ir0 = (int)floorf(rr);
    int iz0 = (int)floorf(zz);
    ir0 = min(max(ir0, 0), NR - 2);
    iz0 = min(max(iz0, 0), NZ - 2);
    float dx = rr - (float)ir0;
    float dz = zz - (float)iz0;
    float wx = 1.0f - dx;
    float wz = 1.0f - dz;
    uv2 g = Pb[(ir0 << 9) + iz0];             // single aligned 8B gather
    float f11 = __uint_as_float(g.x << 16);
    float f21 = __uint_as_float(g.x & 0xFFFF0000u);
    float f12 = __uint_as_float(g.y << 16);
    float f22 = __uint_as_float(g.y & 0xFFFF0000u);
    return wx * (f11 * wz + f12 * dz) + dx * (f21 * wz + f22 * dz);
}

__global__ void __launch_bounds__(BLOCK) interp_bf16(
    const float* __restrict__ r, const float* __restrict__ z,
    const uv2* __restrict__ Pb, float* __restrict__ out, int nvec) {
    const int tid = threadIdx.x;
    const int base = blockIdx.x * (BLOCK * VPT) + tid;
    const bool full = (blockIdx.x + 1) * (BLOCK * VPT) <= nvec;

    if (full) {
        vf4 rv[VPT], zv[VPT];
#pragma unroll
        for (int k = 0; k < VPT; ++k) {
            rv[k] = __builtin_nontemporal_load(
                reinterpret_cast<const vf4*>(r) + base + k * BLOCK);
            zv[k] = __builtin_nontemporal_load(
                reinterpret_cast<const vf4*>(z) + base + k * BLOCK);
        }
#pragma unroll
        for (int k = 0; k < VPT; ++k) {
            vf4 o;
            o.x = interp_one(rv[k].x, zv[k].x, Pb);
            o.y = interp_one(rv[k].y, zv[k].y, Pb);
            o.z = interp_one(rv[k].z, zv[k].z, Pb);
            o.w = interp_one(rv[k].w, zv[k].w, Pb);
            __builtin_nontemporal_store(o, reinterpret_cast<vf4*>(out) + base + k * BLOCK);
        }
    } else {
#pragma unroll
        for (int k = 0; k < VPT; ++k) {
            const int gv = base + k * BLOCK;
            if (gv < nvec) {
                vf4 rv = reinterpret_cast<const vf4*>(r)[gv];
                vf4 zv = reinterpret_cast<const vf4*>(z)[gv];
                vf4 o;
                o.x = interp_one(rv.x, zv.x, Pb);
                o.y = interp_one(rv.y, zv.y, Pb);
                o.z = interp_one(rv.z, zv.z, Pb);
                o.w = interp_one(rv.w, zv.w, Pb);
                reinterpret_cast<vf4*>(out)[gv] = o;
            }
        }
    }
}

// ---- exact-fp32 scalar tail + fallback path ----
__device__ __forceinline__ float interp_direct(float rr, float zz,
                                               const float* __restrict__ tt) {
    int ir0 = (int)floorf(rr);
    int iz0 = (int)floorf(zz);
    ir0 = min(max(ir0, 0), NR - 2);
    iz0 = min(max(iz0, 0), NZ - 2);
    float dx = rr - (float)ir0, wx = 1.0f - dx;
    float dz = zz - (float)iz0, wz = 1.0f - dz;
    int b = (ir0 << 9) + iz0;
    float Q11 = tt[b], Q12 = tt[b + 1], Q21 = tt[b + NZ], Q22 = tt[b + NZ + 1];
    return (Q11 * wz + Q12 * dz) * wx + (Q21 * wz + Q22 * dz) * dx;
}

__global__ void tail_direct(const float* __restrict__ r, const float* __restrict__ z,
                            const float* __restrict__ tt, float* __restrict__ out,
                            int start, int n) {
    int j = start + blockIdx.x * blockDim.x + threadIdx.x;
    if (j < n) out[j] = interp_direct(r[j], z[j], tt);
}

__global__ void __launch_bounds__(256) interp_direct_kernel(
    const float* __restrict__ r, const float* __restrict__ z,
    const float* __restrict__ tt, float* __restrict__ out, int n4) {
    int i = blockIdx.x * blockDim.x + threadIdx.x;
    if (i < n4) {
        vf4 rv = reinterpret_cast<const vf4*>(r)[i];
        vf4 zv = reinterpret_cast<const vf4*>(z)[i];
        vf4 o;
        o.x = interp_direct(rv.x, zv.x, tt);
        o.y = interp_direct(rv.y, zv.y, tt);
        o.z = interp_direct(rv.z, zv.z, tt);
        o.w = interp_direct(rv.w, zv.w, tt);
        reinterpret_cast<vf4*>(out)[i] = o;
    }
}

extern "C" void kernel_launch(void* const* d_in, const int* in_sizes, int n_in,
                              void* d_out, int out_size, void* d_ws, size_t ws_size,
                              hipStream_t stream) {
    const float* r  = (const float*)d_in[0];
    const float* z  = (const float*)d_in[1];
    const float* tt = (const float*)d_in[2];
    float* out = (float*)d_out;
    const int n = in_sizes[0];
    const int nvec = n / 4;
    const int tail = n - nvec * 4;

    const size_t need = (size_t)P_ELEMS * sizeof(uv2);   // ~2.09 MB
    if (ws_size >= need) {
        uv2* Pb = (uv2*)d_ws;
        build_bf16<<<(P_ELEMS + 255) / 256, 256, 0, stream>>>(tt, Pb);
        const int blocks = (nvec + BLOCK * VPT - 1) / (BLOCK * VPT);
        interp_bf16<<<blocks, BLOCK, 0, stream>>>(r, z, Pb, out, nvec);
    } else {
        interp_direct_kernel<<<(nvec + 255) / 256, 256, 0, stream>>>(r, z, tt, out, nvec);
    }
    if (tail > 0)
        tail_direct<<<1, 64, 0, stream>>>(r, z, tt, out, nvec * 4, n);
}